// Round 10
// baseline (325.452 us; speedup 1.0000x reference)
//
#include <hip/hip_runtime.h>

#define S 64
#define ST 68    // stride (floats) for 64-col LDS tiles; rows 16B-aligned; 2-way banks
#define STW 132  // stride for Wfc rows (128 cols + pad); 16B-aligned; 2-way banks
#define E_EDGES 256
#define NT 512
#define N_NODES 32768
#define NPB 128    // nodes per block (static copy range)
#define NPAIRS 64  // 2-node copy groups per block

__device__ __forceinline__ float v_rcp(float x) {
  float r;
  asm("v_rcp_f32 %0, %1" : "=v"(r) : "v"(x));
  return r;
}

// tanh(x) = 1 - 2/(exp2(2*log2e*x)+1); ~1e-7 rel err, branch-free
__device__ __forceinline__ float tanh_term(float x) {
  float t = __builtin_amdgcn_exp2f(x * 2.88539008177793f);
  return fmaf(-2.0f, v_rcp(t + 1.0f), 1.0f);
}

// zero done flags, build touched-node bitmap (global)
__global__ void init_kernel(const int* __restrict__ edges, int* __restrict__ done,
                            unsigned int* __restrict__ bitmap) {
  const int tid = threadIdx.x;  // 1024 threads, 1 block
  if (tid < E_EDGES) done[tid] = 0;
  bitmap[tid] = 0u;
  __syncthreads();
  if (tid < 2 * E_EDGES) {
    int node = edges[tid];
    atomicOr(&bitmap[node >> 5], 1u << (node & 31));
  }
}

__global__ __launch_bounds__(NT, 1) void fused_kernel(
    const float* __restrict__ inputs,
    const int* __restrict__ masks,
    const int* __restrict__ edges,
    const float* __restrict__ Wq,
    const float* __restrict__ Wk,
    const float* __restrict__ wv,
    const float* __restrict__ Wfc,
    const float* __restrict__ bfc,
    float* __restrict__ out,
    int* __restrict__ done,
    const unsigned int* __restrict__ bitmap) {
  const int tid = threadIdx.x;
  const int e = blockIdx.x;
  const int lane = tid & 63;
  const int wvid = tid >> 6;

  __shared__ float sWqT[S][ST];   // transposed: sWqT[j][h] = Wq[h][j]
  __shared__ float sWkT[S][ST];
  __shared__ float sWfc[S][STW];  // normal: sWfc[h][r], r<128
  __shared__ float sEx[S][ST];
  __shared__ float sEy[S][ST];
  __shared__ float sQ[S][ST];
  __shared__ float sK[S][ST];
  __shared__ float sP[S][ST];
  __shared__ float swv[S];
  __shared__ float sbfc[S];
  __shared__ int sMeta[4];  // depA, depB, validA, validB
  __shared__ int sEBar;     // edge-team barrier counter (monotonic)
  __shared__ int sCIdx;     // copy work counter

  if (tid == 0) {
    sMeta[0] = -1;
    sMeta[1] = -1;
    sEBar = 0;
    sCIdx = 0;
  }
  __syncthreads();  // the ONLY block-wide barrier (all 8 waves present)

  const int a = edges[e];
  const int b = edges[E_EDGES + e];

  // shared copy worker: grab 2-node groups; 16 f4 loads in flight per node
  // (16 KB/wave), stores predicated on wave-uniform bitmap test
  auto copy_work = [&]() {
    for (;;) {
      int g;
      if (lane == 0) g = atomicAdd(&sCIdx, 1);
      g = __shfl(g, 0, 64);
      if (g >= NPAIRS) break;
      const int n0 = e * NPB + 2 * g;
#pragma unroll
      for (int nn = 0; nn < 2; ++nn) {
        const int n = n0 + nn;
        const bool skip = (bitmap[n >> 5] >> (n & 31)) & 1u;  // uniform
        const float4* __restrict__ src = (const float4*)inputs + (size_t)n * 1024;
        float4* __restrict__ dst = (float4*)out + (size_t)n * 1024;
        float4 v[16];
#pragma unroll
        for (int k = 0; k < 16; ++k) v[k] = src[lane + 64 * k];
        if (!skip) {
#pragma unroll
          for (int k = 0; k < 16; ++k) dst[lane + 64 * k] = v[k];
        }
      }
    }
  };

  // ---------------- copy team: waves 4..7 ----------------
  if (wvid >= 4) {
    copy_work();
    return;
  }

  // ---------------- edge team: waves 0..3 (256 threads) ----------------
  int ph = 0;
  auto ebar = [&]() {  // team barrier among 4 edge waves via LDS atomics
    ph += 4;
    if ((tid & 63) == 0)
      __hip_atomic_fetch_add(&sEBar, 1, __ATOMIC_ACQ_REL, __HIP_MEMORY_SCOPE_WORKGROUP);
    while (__hip_atomic_load(&sEBar, __ATOMIC_ACQUIRE, __HIP_MEMORY_SCOPE_WORKGROUP) < ph)
      __builtin_amdgcn_s_sleep(1);
  };

  // stage weights: Wq/Wk transposed, Wfc rows, wv/bfc
#pragma unroll
  for (int k = 0; k < 4; ++k) {
    int i4 = tid + k * 256;  // 0..1023
    int h = i4 >> 4, j0 = (i4 & 15) << 2;
    float4 q4 = *(const float4*)(Wq + h * S + j0);
    float4 k4 = *(const float4*)(Wk + h * S + j0);
    sWqT[j0 + 0][h] = q4.x; sWqT[j0 + 1][h] = q4.y;
    sWqT[j0 + 2][h] = q4.z; sWqT[j0 + 3][h] = q4.w;
    sWkT[j0 + 0][h] = k4.x; sWkT[j0 + 1][h] = k4.y;
    sWkT[j0 + 2][h] = k4.z; sWkT[j0 + 3][h] = k4.w;
  }
#pragma unroll
  for (int k = 0; k < 8; ++k) {
    int i4 = tid + k * 256;  // 0..2047
    int h = i4 >> 5, r0 = (i4 & 31) << 2;
    *(float4*)&sWfc[h][r0] = *(const float4*)(Wfc + h * 2 * S + r0);
  }
  if (tid < S) { swv[tid] = wv[tid]; sbfc[tid] = bfc[tid]; }

  // dep scan: latest earlier edge touching node a / node b
  if (tid < e) {
    int xa = edges[tid], yb = edges[E_EDGES + tid];
    if (xa == a || yb == a) atomicMax(&sMeta[0], tid);
    if (xa == b || yb == b) atomicMax(&sMeta[1], tid);
  }

  // valid lengths (wave 0 -> a, wave 1 -> b)
  int mv = 0;
  if (wvid == 0) mv = masks[(size_t)a * S + lane];
  else if (wvid == 1) mv = masks[(size_t)b * S + lane];
#pragma unroll
  for (int d = 1; d < 64; d <<= 1) mv += __shfl_xor(mv, d, 64);
  if (tid == 0) sMeta[2] = mv;
  if (tid == 64) sMeta[3] = mv;

  ebar();  // #1: deps + valids visible

  const int depA = sMeta[0], depB = sMeta[1];
  const int validA = sMeta[2], validB = sMeta[3];

  // RELAXED spin on deps (no per-iteration invalidate), then ONE acquire each
  if (tid == 0) {
    if (depA >= 0) {
      while (__hip_atomic_load(&done[depA], __ATOMIC_RELAXED, __HIP_MEMORY_SCOPE_AGENT) == 0)
        __builtin_amdgcn_s_sleep(16);
      (void)__hip_atomic_load(&done[depA], __ATOMIC_ACQUIRE, __HIP_MEMORY_SCOPE_AGENT);
    }
    if (depB >= 0) {
      while (__hip_atomic_load(&done[depB], __ATOMIC_RELAXED, __HIP_MEMORY_SCOPE_AGENT) == 0)
        __builtin_amdgcn_s_sleep(16);
      (void)__hip_atomic_load(&done[depB], __ATOMIC_ACQUIRE, __HIP_MEMORY_SCOPE_AGENT);
    }
  }
  ebar();  // #2: deps satisfied

  // stage embeddings (first touch from inputs, else chain state in out)
  const float* exg = (depA >= 0) ? out + (size_t)a * 4096 : inputs + (size_t)a * 4096;
  const float* eyg = (depB >= 0) ? out + (size_t)b * 4096 : inputs + (size_t)b * 4096;
#pragma unroll
  for (int k = 0; k < 4; ++k) {
    int i4 = tid + k * 256;
    int r = i4 >> 4, c4 = (i4 & 15) << 2;
    *(float4*)&sEx[r][c4] = *(const float4*)(exg + r * S + c4);
    *(float4*)&sEy[r][c4] = *(const float4*)(eyg + r * S + c4);
  }
  ebar();  // #3: embeddings staged

  const int ty = tid >> 4;      // 0..15
  const int tx = tid & 15;      // 0..15
  const int c0 = tx << 2;       // 4 cols
  // rows per thread: ty + 16*s (strided -> 2-way LDS banks = free)

  // D[i][h] = sum_j A[i][j] * WT[j][h]
  auto proj = [&](const float (*A)[ST], const float (*WT)[ST], float (*D)[ST]) {
    float acc[4][4] = {};
    for (int j0 = 0; j0 < S; j0 += 4) {
      float4 av[4];
#pragma unroll
      for (int s = 0; s < 4; ++s) av[s] = *(const float4*)&A[ty + 16 * s][j0];
#pragma unroll
      for (int jj = 0; jj < 4; ++jj) {
        float4 w4 = *(const float4*)&WT[j0 + jj][c0];
#pragma unroll
        for (int s = 0; s < 4; ++s) {
          float as = (&av[s].x)[jj];
          acc[s][0] = fmaf(as, w4.x, acc[s][0]);
          acc[s][1] = fmaf(as, w4.y, acc[s][1]);
          acc[s][2] = fmaf(as, w4.z, acc[s][2]);
          acc[s][3] = fmaf(as, w4.w, acc[s][3]);
        }
      }
    }
#pragma unroll
    for (int s = 0; s < 4; ++s)
      *(float4*)&D[ty + 16 * s][c0] = make_float4(acc[s][0], acc[s][1], acc[s][2], acc[s][3]);
  };

  // scores -> sP; cols cu = tx + 16u; masked cols in rounded range get 0.0f
  auto score_phase = [&](int vlen) {
    if (vlen == 0) {  // softmax of all -1e6 = uniform 1/64
#pragma unroll
      for (int u = 0; u < 4; ++u)
#pragma unroll
        for (int s = 0; s < 4; ++s) sP[ty + 16 * s][tx + 16 * u] = 0.015625f;
      return;
    }
    float acc[4][4] = {};
    for (int h0 = 0; h0 < S; h0 += 4) {
      float4 q4[4];
#pragma unroll
      for (int s = 0; s < 4; ++s) q4[s] = *(const float4*)&sQ[ty + 16 * s][h0];
      float4 wv4 = *(const float4*)&swv[h0];
#pragma unroll
      for (int u = 0; u < 4; ++u) {
        if (16 * u < vlen) {  // wave-uniform chunk skip
          float4 k4 = *(const float4*)&sK[tx + 16 * u][h0];
#pragma unroll
          for (int jj = 0; jj < 4; ++jj) {
            float kk = (&k4.x)[jj];
            float wvh = (&wv4.x)[jj];
#pragma unroll
            for (int s = 0; s < 4; ++s)
              acc[s][u] = fmaf(tanh_term((&q4[s].x)[jj] + kk), wvh, acc[s][u]);
          }
        }
      }
    }
#pragma unroll
    for (int u = 0; u < 4; ++u) {
      int cu = tx + 16 * u;
#pragma unroll
      for (int s = 0; s < 4; ++s)
        sP[ty + 16 * s][cu] = (cu < vlen) ? acc[s][u] : 0.0f;  // zeros feed pv tail
    }
  };

  // row softmax over cols < vlen: 4 lanes per row
  auto softmax_phase = [&](int vlen) {
    if (vlen == 0) return;
    const int row = tid >> 2, sub = tid & 3;
    float m = -3.0e38f;
#pragma unroll
    for (int k = 0; k < 16; ++k) {
      int c = sub + 4 * k;
      if (c < vlen) m = fmaxf(m, sP[row][c]);
    }
#pragma unroll
    for (int d = 1; d < 4; d <<= 1) m = fmaxf(m, __shfl_xor(m, d, 4));
    float p[16];
    float sum = 0.f;
#pragma unroll
    for (int k = 0; k < 16; ++k) {
      int c = sub + 4 * k;
      if (c < vlen) {
        p[k] = __expf(sP[row][c] - m);
        sum += p[k];
      }
    }
#pragma unroll
    for (int d = 1; d < 4; d <<= 1) sum += __shfl_xor(sum, d, 4);
    float inv = 1.0f / sum;
#pragma unroll
    for (int k = 0; k < 16; ++k) {
      int c = sub + 4 * k;
      if (c < vlen) sP[row][c] = p[k] * inv;
    }
  };

  // D[i][j] = sum_k P[i][k] * V[k][j]; k truncated to rounded vlen (zeros beyond)
  auto pv_phase = [&](const float (*V)[ST], float (*D)[ST], int vlen) {
    const int kEnd = (vlen == 0) ? S : ((vlen + 3) & ~3);
    float acc[4][4] = {};
    for (int k0 = 0; k0 < kEnd; k0 += 4) {
      float4 p4[4];
#pragma unroll
      for (int s = 0; s < 4; ++s) p4[s] = *(const float4*)&sP[ty + 16 * s][k0];
#pragma unroll
      for (int kk = 0; kk < 4; ++kk) {
        float4 v4 = *(const float4*)&V[k0 + kk][c0];
#pragma unroll
        for (int s = 0; s < 4; ++s) {
          float ps = (&p4[s].x)[kk];
          acc[s][0] = fmaf(ps, v4.x, acc[s][0]);
          acc[s][1] = fmaf(ps, v4.y, acc[s][1]);
          acc[s][2] = fmaf(ps, v4.z, acc[s][2]);
          acc[s][3] = fmaf(ps, v4.w, acc[s][3]);
        }
      }
    }
#pragma unroll
    for (int s = 0; s < 4; ++s)
      *(float4*)&D[ty + 16 * s][c0] = make_float4(acc[s][0], acc[s][1], acc[s][2], acc[s][3]);
  };

  // out[h][c] = bfc[h] + sum_r Wfc[h][r]*E1[r][c] + sum_r Wfc[h][64+r]*A1[r][c]
  auto fc_phase = [&](const float (*E1)[ST], const float (*A1)[ST], float* outg) {
    float acc[4][4];
#pragma unroll
    for (int s = 0; s < 4; ++s) {
      float bv = sbfc[ty + 16 * s];
      acc[s][0] = bv; acc[s][1] = bv; acc[s][2] = bv; acc[s][3] = bv;
    }
    for (int r0 = 0; r0 < S; r0 += 4) {
      float4 w4[4];
#pragma unroll
      for (int s = 0; s < 4; ++s) w4[s] = *(const float4*)&sWfc[ty + 16 * s][r0];
#pragma unroll
      for (int rr = 0; rr < 4; ++rr) {
        float4 e4 = *(const float4*)&E1[r0 + rr][c0];
#pragma unroll
        for (int s = 0; s < 4; ++s) {
          float ws = (&w4[s].x)[rr];
          acc[s][0] = fmaf(ws, e4.x, acc[s][0]);
          acc[s][1] = fmaf(ws, e4.y, acc[s][1]);
          acc[s][2] = fmaf(ws, e4.z, acc[s][2]);
          acc[s][3] = fmaf(ws, e4.w, acc[s][3]);
        }
      }
    }
    for (int r0 = 0; r0 < S; r0 += 4) {
      float4 w4[4];
#pragma unroll
      for (int s = 0; s < 4; ++s) w4[s] = *(const float4*)&sWfc[ty + 16 * s][S + r0];
#pragma unroll
      for (int rr = 0; rr < 4; ++rr) {
        float4 e4 = *(const float4*)&A1[r0 + rr][c0];
#pragma unroll
        for (int s = 0; s < 4; ++s) {
          float ws = (&w4[s].x)[rr];
          acc[s][0] = fmaf(ws, e4.x, acc[s][0]);
          acc[s][1] = fmaf(ws, e4.y, acc[s][1]);
          acc[s][2] = fmaf(ws, e4.z, acc[s][2]);
          acc[s][3] = fmaf(ws, e4.w, acc[s][3]);
        }
      }
    }
#pragma unroll
    for (int s = 0; s < 4; ++s)
      *(float4*)(outg + (size_t)(ty + 16 * s) * S + c0) =
          make_float4(acc[s][0], acc[s][1], acc[s][2], acc[s][3]);
  };

  // ---- attention 1: q from ex, kv = ey, vlen = valid[a] ----
  proj(sEx, sWqT, sQ);
  proj(sEy, sWkT, sK);
  ebar();  // #4
  score_phase(validA);
  ebar();  // #5
  softmax_phase(validA);
  ebar();  // #6
  pv_phase(sEy, sQ, validA);  // sQ := y2x
  ebar();  // #7
  fc_phase(sEx, sQ, out + (size_t)a * 4096);
  ebar();  // #8 (protect sQ/sK until fc reads done)

  // ---- attention 2: q from ey, kv = ex, vlen = valid[b] ----
  proj(sEy, sWqT, sQ);
  proj(sEx, sWkT, sK);
  ebar();  // #9
  score_phase(validB);
  ebar();  // #10
  softmax_phase(validB);
  ebar();  // #11
  pv_phase(sEx, sQ, validB);  // sQ := x2y
  ebar();  // #12
  fc_phase(sEy, sQ, out + (size_t)b * 4096);  // y written last -> wins on self-loop

  // drain this wave's global stores, team-sync, then agent-release done[e]
  asm volatile("s_waitcnt vmcnt(0)" ::: "memory");
  ebar();  // #13
  if (tid == 0)
    __hip_atomic_store(&done[e], 1, __ATOMIC_RELEASE, __HIP_MEMORY_SCOPE_AGENT);

  // edge team joins the copy
  copy_work();
}

extern "C" void kernel_launch(void* const* d_in, const int* in_sizes, int n_in,
                              void* d_out, int out_size, void* d_ws, size_t ws_size,
                              hipStream_t stream) {
  const float* inputs = (const float*)d_in[0];
  const int* masks = (const int*)d_in[1];
  const int* edges = (const int*)d_in[2];
  const float* Wq = (const float*)d_in[3];
  const float* Wk = (const float*)d_in[4];
  const float* wv = (const float*)d_in[5];
  const float* Wfc = (const float*)d_in[6];
  const float* bfc = (const float*)d_in[7];
  float* out = (float*)d_out;
  int* done = (int*)d_ws;                                  // 256 ints
  unsigned int* bitmap = (unsigned int*)(done + E_EDGES);  // 1024 words

  init_kernel<<<1, 1024, 0, stream>>>(edges, done, bitmap);
  fused_kernel<<<E_EDGES, NT, 0, stream>>>(inputs, masks, edges, Wq, Wk, wv, Wfc,
                                           bfc, out, done, bitmap);
}

// Round 11
// 268.418 us; speedup vs baseline: 1.2125x; 1.2125x over previous
//
#include <hip/hip_runtime.h>

#define S 64
#define ST 68    // stride (floats) for 64-col LDS tiles; rows 16B-aligned; 2-way banks free
#define STW 132  // stride for Wfc rows (128 cols + pad)
#define E_EDGES 256
#define NT 512
#define N_NODES 32768
#define NPB 128    // nodes per block (static copy range)
#define NPAIRS 64  // 2-node copy groups per block

__device__ __forceinline__ float v_rcp(float x) {
  float r;
  asm("v_rcp_f32 %0, %1" : "=v"(r) : "v"(x));
  return r;
}

// tanh(x) = 1 - 2/(exp2(2*log2e*x)+1); ~1e-7 rel err, branch-free
__device__ __forceinline__ float tanh_term(float x) {
  float t = __builtin_amdgcn_exp2f(x * 2.88539008177793f);
  return fmaf(-2.0f, v_rcp(t + 1.0f), 1.0f);
}

// zero done flags, build touched-node bitmap
__global__ void init_kernel(const int* __restrict__ edges, int* __restrict__ done,
                            unsigned int* __restrict__ bitmap) {
  const int tid = threadIdx.x;  // 1024 threads, 1 block
  if (tid < E_EDGES) done[tid] = 0;
  bitmap[tid] = 0u;
  __syncthreads();
  if (tid < 2 * E_EDGES) {
    int node = edges[tid];
    atomicOr(&bitmap[node >> 5], 1u << (node & 31));
  }
}

__global__ __launch_bounds__(NT, 1) void fused_kernel(
    const float* __restrict__ inputs,
    const int* __restrict__ masks,
    const int* __restrict__ edges,
    const float* __restrict__ Wq,
    const float* __restrict__ Wk,
    const float* __restrict__ wv,
    const float* __restrict__ Wfc,
    const float* __restrict__ bfc,
    float* __restrict__ out,
    int* __restrict__ done,
    const unsigned int* __restrict__ bitmap) {
  const int tid = threadIdx.x;
  const int e = blockIdx.x;
  const int lane = tid & 63;
  const int wvid = tid >> 6;

  __shared__ float sWqT[S][ST];   // transposed: sWqT[j][h] = Wq[h][j]
  __shared__ float sWkT[S][ST];
  __shared__ float sWfc[S][STW];  // sWfc[h][r], r<128
  __shared__ float sEx[S][ST];
  __shared__ float sEy[S][ST];
  __shared__ float sQ[S][ST];
  __shared__ float sK[S][ST];
  __shared__ float sP[S][ST];
  __shared__ float swv[S];
  __shared__ float sbfc[S];
  __shared__ unsigned int sBitmap[N_NODES / 32];  // 4 KB
  __shared__ int sMeta[4];  // depA, depB, validA, validB

  const int a = edges[e];
  const int b = edges[E_EDGES + e];

  if (tid < 2) sMeta[tid] = -1;
  __syncthreads();
  // latest earlier edge touching node a / node b
  if (tid < e) {
    int xa = edges[tid], yb = edges[E_EDGES + tid];
    if (xa == a || yb == a) atomicMax(&sMeta[0], tid);
    if (xa == b || yb == b) atomicMax(&sMeta[1], tid);
  }

  // stage weights (transposed Wq/Wk), Wfc, wv/bfc, bitmap
#pragma unroll
  for (int k = 0; k < 2; ++k) {
    int i4 = tid + k * NT;  // 0..1023
    int h = i4 >> 4, j0 = (i4 & 15) << 2;
    float4 q4 = *(const float4*)(Wq + h * S + j0);
    float4 k4 = *(const float4*)(Wk + h * S + j0);
    sWqT[j0 + 0][h] = q4.x; sWqT[j0 + 1][h] = q4.y;
    sWqT[j0 + 2][h] = q4.z; sWqT[j0 + 3][h] = q4.w;
    sWkT[j0 + 0][h] = k4.x; sWkT[j0 + 1][h] = k4.y;
    sWkT[j0 + 2][h] = k4.z; sWkT[j0 + 3][h] = k4.w;
  }
#pragma unroll
  for (int k = 0; k < 4; ++k) {
    int i4 = tid + k * NT;  // 0..2047
    int h = i4 >> 5, r0 = (i4 & 31) << 2;
    *(float4*)&sWfc[h][r0] = *(const float4*)(Wfc + h * 2 * S + r0);
  }
  if (tid < S) { swv[tid] = wv[tid]; sbfc[tid] = bfc[tid]; }
  sBitmap[tid] = bitmap[tid];
  sBitmap[tid + NT] = bitmap[tid + NT];

  // valid lengths
  int mv = 0;
  if (wvid == 0) mv = masks[(size_t)a * S + lane];
  else if (wvid == 1) mv = masks[(size_t)b * S + lane];
#pragma unroll
  for (int d = 1; d < 64; d <<= 1) mv += __shfl_xor(mv, d, 64);
  if (tid == 0) sMeta[2] = mv;
  if (tid == 64) sMeta[3] = mv;

  __syncthreads();
  const int depA = sMeta[0], depB = sMeta[1];
  const int validA = sMeta[2], validB = sMeta[3];

  // copy pair p of this block's static range: 4 f4 loads over a contiguous
  // 32 KB span, tight predicated stores (1x HBM writes; bitmap test uniform)
  auto copy_pair = [&](int p) {
    const int n0 = e * NPB + 2 * p;
    const int n1 = n0 + 1;
    const size_t f4 = (size_t)n0 * 1024;
    const float4* __restrict__ src = (const float4*)inputs + f4;
    float4* __restrict__ dst = (float4*)out + f4;
    float4 v0 = src[tid];
    float4 v1 = src[tid + 512];
    float4 v2 = src[tid + 1024];
    float4 v3 = src[tid + 1536];
    if (!(sBitmap[n0 >> 5] & (1u << (n0 & 31)))) {
      dst[tid] = v0;
      dst[tid + 512] = v1;
    }
    if (!(sBitmap[n1 >> 5] & (1u << (n1 & 31)))) {
      dst[tid + 1024] = v2;
      dst[tid + 1536] = v3;
    }
  };

  // dep blocks copy own range while polling (RELAXED spin); then ONE acquire per dep
  int g = 0;
  if (depA >= 0 || depB >= 0) {
    for (;;) {
      __syncthreads();
      if (tid == 0) {
        int ok = 1;
        if (depA >= 0 &&
            __hip_atomic_load(&done[depA], __ATOMIC_RELAXED, __HIP_MEMORY_SCOPE_AGENT) == 0)
          ok = 0;
        if (ok && depB >= 0 &&
            __hip_atomic_load(&done[depB], __ATOMIC_RELAXED, __HIP_MEMORY_SCOPE_AGENT) == 0)
          ok = 0;
        sMeta[3 + 1] = 0;  // unused slot guard (no-op)
        ((volatile int*)sMeta)[0] = depA;  // keep sMeta stable
        ((volatile int*)sMeta)[1] = depB;
        *((volatile int*)&sMeta[2]) = validA;
        sMeta[3] = validB;
        // store readiness in a dedicated slot via sMeta reuse is risky; use shfl below
        ((volatile int*)sMeta)[3] = validB;
        // readiness flag:
        ((volatile int*)&sBitmap[N_NODES / 32 - 1]);  // no-op
        // simpler: broadcast via LDS int
        *((volatile int*)&swv[0]) = 0;  // placeholder (overwritten below anyway)
        ((volatile int*)sMeta)[0] = depA;
        // Use a separate flag word:
        sP[0][ST - 1] = ok ? 1.0f : 0.0f;
      }
      __syncthreads();
      if (sP[0][ST - 1] != 0.0f) break;
      if (g < NPAIRS) {
        copy_pair(g);
        copy_pair(g + 1);
        g += 2;
      } else {
        __builtin_amdgcn_s_sleep(16);
      }
    }
    if (tid == 0) {
      if (depA >= 0)
        (void)__hip_atomic_load(&done[depA], __ATOMIC_ACQUIRE, __HIP_MEMORY_SCOPE_AGENT);
      if (depB >= 0)
        (void)__hip_atomic_load(&done[depB], __ATOMIC_ACQUIRE, __HIP_MEMORY_SCOPE_AGENT);
    }
    __syncthreads();
  }

  // stage embeddings (first touch from inputs, else chain state in out)
  const float* exg = (depA >= 0) ? out + (size_t)a * 4096 : inputs + (size_t)a * 4096;
  const float* eyg = (depB >= 0) ? out + (size_t)b * 4096 : inputs + (size_t)b * 4096;
#pragma unroll
  for (int k = 0; k < 2; ++k) {
    int i4 = tid + k * NT;
    int r = i4 >> 4, c4 = (i4 & 15) << 2;
    *(float4*)&sEx[r][c4] = *(const float4*)(exg + r * S + c4);
    *(float4*)&sEy[r][c4] = *(const float4*)(eyg + r * S + c4);
  }
  __syncthreads();

  // --- thread tiling: rows {ty, ty+32}, cols c0..c0+3 ---
  const int ty = tid >> 4;  // 0..31
  const int tx = tid & 15;  // 0..15
  const int c0 = tx << 2;

  // D[i][h] = sum_j A[i][j] * WT[j][h]
  auto proj = [&](const float (*A)[ST], const float (*WT)[ST], float (*D)[ST]) {
    float acc[2][4] = {};
#pragma unroll 4
    for (int j0 = 0; j0 < S; j0 += 4) {
      float4 av[2];
      av[0] = *(const float4*)&A[ty][j0];
      av[1] = *(const float4*)&A[ty + 32][j0];
#pragma unroll
      for (int jj = 0; jj < 4; ++jj) {
        float4 w4 = *(const float4*)&WT[j0 + jj][c0];
#pragma unroll
        for (int s = 0; s < 2; ++s) {
          float as = (&av[s].x)[jj];
          acc[s][0] = fmaf(as, w4.x, acc[s][0]);
          acc[s][1] = fmaf(as, w4.y, acc[s][1]);
          acc[s][2] = fmaf(as, w4.z, acc[s][2]);
          acc[s][3] = fmaf(as, w4.w, acc[s][3]);
        }
      }
    }
    *(float4*)&D[ty][c0] = make_float4(acc[0][0], acc[0][1], acc[0][2], acc[0][3]);
    *(float4*)&D[ty + 32][c0] = make_float4(acc[1][0], acc[1][1], acc[1][2], acc[1][3]);
  };

  // scores -> sP; cols cu = tx + 16u; wave-uniform chunk skip; masked cols get 0.0f
  auto score_phase = [&](int vlen) {
    if (vlen == 0) {  // softmax of all -1e6 = uniform 1/64
#pragma unroll
      for (int u = 0; u < 4; ++u) {
        sP[ty][tx + 16 * u] = 0.015625f;
        sP[ty + 32][tx + 16 * u] = 0.015625f;
      }
      return;
    }
    float acc[2][4] = {};
#pragma unroll 2
    for (int h0 = 0; h0 < S; h0 += 4) {
      float4 q4[2];
      q4[0] = *(const float4*)&sQ[ty][h0];
      q4[1] = *(const float4*)&sQ[ty + 32][h0];
      float4 wv4 = *(const float4*)&swv[h0];
#pragma unroll
      for (int u = 0; u < 4; ++u) {
        if (16 * u < vlen) {  // wave-uniform chunk skip
          float4 k4 = *(const float4*)&sK[tx + 16 * u][h0];
#pragma unroll
          for (int jj = 0; jj < 4; ++jj) {
            float kk = (&k4.x)[jj];
            float wvh = (&wv4.x)[jj];
            acc[0][u] = fmaf(tanh_term((&q4[0].x)[jj] + kk), wvh, acc[0][u]);
            acc[1][u] = fmaf(tanh_term((&q4[1].x)[jj] + kk), wvh, acc[1][u]);
          }
        }
      }
    }
#pragma unroll
    for (int u = 0; u < 4; ++u) {
      int cu = tx + 16 * u;
      sP[ty][cu] = (cu < vlen) ? acc[0][u] : 0.0f;      // zeros feed pv tail
      sP[ty + 32][cu] = (cu < vlen) ? acc[1][u] : 0.0f;
    }
  };

  // row softmax over cols < vlen: 8 lanes per row
  auto softmax_phase = [&](int vlen) {
    if (vlen == 0) return;  // already uniform
    const int row = tid >> 3, sub = tid & 7;
    float m = -3.0e38f;
#pragma unroll
    for (int k = 0; k < 8; ++k) {
      int c = sub + 8 * k;
      if (c < vlen) m = fmaxf(m, sP[row][c]);
    }
#pragma unroll
    for (int d = 1; d < 8; d <<= 1) m = fmaxf(m, __shfl_xor(m, d, 8));
    float p[8];
    float sum = 0.f;
#pragma unroll
    for (int k = 0; k < 8; ++k) {
      int c = sub + 8 * k;
      if (c < vlen) {
        p[k] = __expf(sP[row][c] - m);
        sum += p[k];
      }
    }
#pragma unroll
    for (int d = 1; d < 8; d <<= 1) sum += __shfl_xor(sum, d, 8);
    float inv = 1.0f / sum;
#pragma unroll
    for (int k = 0; k < 8; ++k) {
      int c = sub + 8 * k;
      if (c < vlen) sP[row][c] = p[k] * inv;
    }
  };

  // D[i][j] = sum_k P[i][k] * V[k][j]; k truncated to rounded vlen (zeros beyond)
  auto pv_phase = [&](const float (*V)[ST], float (*D)[ST], int vlen) {
    const int kEnd = (vlen == 0) ? S : ((vlen + 3) & ~3);
    float acc[2][4] = {};
    for (int k0 = 0; k0 < kEnd; k0 += 4) {
      float4 p4[2];
      p4[0] = *(const float4*)&sP[ty][k0];
      p4[1] = *(const float4*)&sP[ty + 32][k0];
#pragma unroll
      for (int kk = 0; kk < 4; ++kk) {
        float4 v4 = *(const float4*)&V[k0 + kk][c0];
#pragma unroll
        for (int s = 0; s < 2; ++s) {
          float ps = (&p4[s].x)[kk];
          acc[s][0] = fmaf(ps, v4.x, acc[s][0]);
          acc[s][1] = fmaf(ps, v4.y, acc[s][1]);
          acc[s][2] = fmaf(ps, v4.z, acc[s][2]);
          acc[s][3] = fmaf(ps, v4.w, acc[s][3]);
        }
      }
    }
    *(float4*)&D[ty][c0] = make_float4(acc[0][0], acc[0][1], acc[0][2], acc[0][3]);
    *(float4*)&D[ty + 32][c0] = make_float4(acc[1][0], acc[1][1], acc[1][2], acc[1][3]);
  };

  // out[h][c] = bfc[h] + sum_r Wfc[h][r]*E1[r][c] + sum_r Wfc[h][64+r]*A1[r][c]
  auto fc_phase = [&](const float (*E1)[ST], const float (*A1)[ST], float* outg) {
    float acc[2][4];
#pragma unroll
    for (int s = 0; s < 2; ++s) {
      float bv = sbfc[ty + 32 * s];
      acc[s][0] = bv; acc[s][1] = bv; acc[s][2] = bv; acc[s][3] = bv;
    }
#pragma unroll 2
    for (int r0 = 0; r0 < S; r0 += 4) {
      float4 w4[2];
      w4[0] = *(const float4*)&sWfc[ty][r0];
      w4[1] = *(const float4*)&sWfc[ty + 32][r0];
#pragma unroll
      for (int rr = 0; rr < 4; ++rr) {
        float4 e4 = *(const float4*)&E1[r0 + rr][c0];
#pragma unroll
        for (int s = 0; s < 2; ++s) {
          float ws = (&w4[s].x)[rr];
          acc[s][0] = fmaf(ws, e4.x, acc[s][0]);
          acc[s][1] = fmaf(ws, e4.y, acc[s][1]);
          acc[s][2] = fmaf(ws, e4.z, acc[s][2]);
          acc[s][3] = fmaf(ws, e4.w, acc[s][3]);
        }
      }
    }
#pragma unroll 2
    for (int r0 = 0; r0 < S; r0 += 4) {
      float4 w4[2];
      w4[0] = *(const float4*)&sWfc[ty][S + r0];
      w4[1] = *(const float4*)&sWfc[ty + 32][S + r0];
#pragma unroll
      for (int rr = 0; rr < 4; ++rr) {
        float4 e4 = *(const float4*)&A1[r0 + rr][c0];
#pragma unroll
        for (int s = 0; s < 2; ++s) {
          float ws = (&w4[s].x)[rr];
          acc[s][0] = fmaf(ws, e4.x, acc[s][0]);
          acc[s][1] = fmaf(ws, e4.y, acc[s][1]);
          acc[s][2] = fmaf(ws, e4.z, acc[s][2]);
          acc[s][3] = fmaf(ws, e4.w, acc[s][3]);
        }
      }
    }
    *(float4*)(outg + (size_t)ty * S + c0) =
        make_float4(acc[0][0], acc[0][1], acc[0][2], acc[0][3]);
    *(float4*)(outg + (size_t)(ty + 32) * S + c0) =
        make_float4(acc[1][0], acc[1][1], acc[1][2], acc[1][3]);
  };

  // ---- attention 1: q from ex, kv = ey, vlen = valid[a] ----
  proj(sEx, sWqT, sQ);
  proj(sEy, sWkT, sK);
  __syncthreads();
  score_phase(validA);
  __syncthreads();
  softmax_phase(validA);
  __syncthreads();
  pv_phase(sEy, sQ, validA);  // sQ := y2x
  __syncthreads();
  fc_phase(sEx, sQ, out + (size_t)a * 4096);
  __syncthreads();

  // ---- attention 2: q from ey, kv = ex, vlen = valid[b] ----
  proj(sEy, sWqT, sQ);
  proj(sEx, sWkT, sK);
  __syncthreads();
  score_phase(validB);
  __syncthreads();
  softmax_phase(validB);
  __syncthreads();
  pv_phase(sEx, sQ, validB);  // sQ := x2y
  __syncthreads();
  fc_phase(sEy, sQ, out + (size_t)b * 4096);  // y written last -> wins on self-loop

  // __syncthreads drains every wave's stores; RELEASE store orders them at agent scope
  __syncthreads();
  if (tid == 0)
    __hip_atomic_store(&done[e], 1, __ATOMIC_RELEASE, __HIP_MEMORY_SCOPE_AGENT);

  // ---- finish this block's static copy range (barrier-free streaming) ----
  for (; g < NPAIRS; ++g) copy_pair(g);
}

extern "C" void kernel_launch(void* const* d_in, const int* in_sizes, int n_in,
                              void* d_out, int out_size, void* d_ws, size_t ws_size,
                              hipStream_t stream) {
  const float* inputs = (const float*)d_in[0];
  const int* masks = (const int*)d_in[1];
  const int* edges = (const int*)d_in[2];
  const float* Wq = (const float*)d_in[3];
  const float* Wk = (const float*)d_in[4];
  const float* wv = (const float*)d_in[5];
  const float* Wfc = (const float*)d_in[6];
  const float* bfc = (const float*)d_in[7];
  float* out = (float*)d_out;
  int* done = (int*)d_ws;                                  // 256 ints
  unsigned int* bitmap = (unsigned int*)(done + E_EDGES);  // 1024 words

  init_kernel<<<1, 1024, 0, stream>>>(edges, done, bitmap);
  fused_kernel<<<E_EDGES, NT, 0, stream>>>(inputs, masks, edges, Wq, Wk, wv, Wfc,
                                           bfc, out, done, bitmap);
}

// Round 12
// 253.019 us; speedup vs baseline: 1.2863x; 1.0609x over previous
//
#include <hip/hip_runtime.h>

#define S 64
#define ST 68    // stride (floats) for 64-col LDS tiles; rows 16B-aligned; 2-way banks free
#define STW 132  // stride for Wfc rows (128 cols + pad)
#define E_EDGES 256
#define NT 512
#define N_NODES 32768
#define NPB 128    // nodes per block (static copy range)
#define NPAIRS 64  // 2-node copy groups per block

__device__ __forceinline__ float v_rcp(float x) {
  float r;
  asm("v_rcp_f32 %0, %1" : "=v"(r) : "v"(x));
  return r;
}

// tanh(x) = 1 - 2/(exp2(2*log2e*x)+1); ~1e-7 rel err, branch-free
__device__ __forceinline__ float tanh_term(float x) {
  float t = __builtin_amdgcn_exp2f(x * 2.88539008177793f);
  return fmaf(-2.0f, v_rcp(t + 1.0f), 1.0f);
}

// zero done flags, build touched-node bitmap
__global__ void init_kernel(const int* __restrict__ edges, int* __restrict__ done,
                            unsigned int* __restrict__ bitmap) {
  const int tid = threadIdx.x;  // 1024 threads, 1 block
  if (tid < E_EDGES) done[tid] = 0;
  bitmap[tid] = 0u;
  __syncthreads();
  if (tid < 2 * E_EDGES) {
    int node = edges[tid];
    atomicOr(&bitmap[node >> 5], 1u << (node & 31));
  }
}

__global__ __launch_bounds__(NT, 1) void fused_kernel(
    const float* __restrict__ inputs,
    const int* __restrict__ masks,
    const int* __restrict__ edges,
    const float* __restrict__ Wq,
    const float* __restrict__ Wk,
    const float* __restrict__ wv,
    const float* __restrict__ Wfc,
    const float* __restrict__ bfc,
    float* __restrict__ out,
    int* __restrict__ done,
    const unsigned int* __restrict__ bitmap) {
  const int tid = threadIdx.x;
  const int e = blockIdx.x;
  const int lane = tid & 63;
  const int wvid = tid >> 6;

  __shared__ float sWqT[S][ST];   // transposed: sWqT[j][h] = Wq[h][j]
  __shared__ float sWkT[S][ST];
  __shared__ float sWfc[S][STW];  // sWfc[h][r], r<128
  __shared__ float sEx[S][ST];
  __shared__ float sEy[S][ST];
  __shared__ float sQ[S][ST];
  __shared__ float sK[S][ST];
  __shared__ float sP[S][ST];
  __shared__ float swv[S];
  __shared__ float sbfc[S];
  __shared__ unsigned int sBitmap[N_NODES / 32];  // 4 KB
  __shared__ int sMeta[6];  // depA, depB, validA, validB, ready, pad

  const int a = edges[e];
  const int b = edges[E_EDGES + e];

  if (tid < 2) sMeta[tid] = -1;
  __syncthreads();
  // latest earlier edge touching node a / node b
  if (tid < e) {
    int xa = edges[tid], yb = edges[E_EDGES + tid];
    if (xa == a || yb == a) atomicMax(&sMeta[0], tid);
    if (xa == b || yb == b) atomicMax(&sMeta[1], tid);
  }

  // stage weights (transposed Wq/Wk), Wfc, wv/bfc, bitmap
#pragma unroll
  for (int k = 0; k < 2; ++k) {
    int i4 = tid + k * NT;  // 0..1023
    int h = i4 >> 4, j0 = (i4 & 15) << 2;
    float4 q4 = *(const float4*)(Wq + h * S + j0);
    float4 k4 = *(const float4*)(Wk + h * S + j0);
    sWqT[j0 + 0][h] = q4.x; sWqT[j0 + 1][h] = q4.y;
    sWqT[j0 + 2][h] = q4.z; sWqT[j0 + 3][h] = q4.w;
    sWkT[j0 + 0][h] = k4.x; sWkT[j0 + 1][h] = k4.y;
    sWkT[j0 + 2][h] = k4.z; sWkT[j0 + 3][h] = k4.w;
  }
#pragma unroll
  for (int k = 0; k < 4; ++k) {
    int i4 = tid + k * NT;  // 0..2047
    int h = i4 >> 5, r0 = (i4 & 31) << 2;
    *(float4*)&sWfc[h][r0] = *(const float4*)(Wfc + h * 2 * S + r0);
  }
  if (tid < S) { swv[tid] = wv[tid]; sbfc[tid] = bfc[tid]; }
  sBitmap[tid] = bitmap[tid];
  sBitmap[tid + NT] = bitmap[tid + NT];

  // valid lengths
  int mv = 0;
  if (wvid == 0) mv = masks[(size_t)a * S + lane];
  else if (wvid == 1) mv = masks[(size_t)b * S + lane];
#pragma unroll
  for (int d = 1; d < 64; d <<= 1) mv += __shfl_xor(mv, d, 64);
  if (tid == 0) sMeta[2] = mv;
  if (tid == 64) sMeta[3] = mv;

  __syncthreads();
  const int depA = sMeta[0], depB = sMeta[1];
  const int validA = sMeta[2], validB = sMeta[3];

  // copy pair p of this block's static range: 4 f4 loads over a contiguous
  // 32 KB span, tight predicated stores (1x HBM writes; bitmap test uniform)
  auto copy_pair = [&](int p) {
    const int n0 = e * NPB + 2 * p;
    const int n1 = n0 + 1;
    const size_t f4 = (size_t)n0 * 1024;
    const float4* __restrict__ src = (const float4*)inputs + f4;
    float4* __restrict__ dst = (float4*)out + f4;
    float4 v0 = src[tid];
    float4 v1 = src[tid + 512];
    float4 v2 = src[tid + 1024];
    float4 v3 = src[tid + 1536];
    if (!(sBitmap[n0 >> 5] & (1u << (n0 & 31)))) {
      dst[tid] = v0;
      dst[tid + 512] = v1;
    }
    if (!(sBitmap[n1 >> 5] & (1u << (n1 & 31)))) {
      dst[tid + 1024] = v2;
      dst[tid + 1536] = v3;
    }
  };

  int g = 0;  // copy progress through this block's 64 pairs
  // boundary copy slot: 2 tight pairs (64 KB), fills the HBM-idle edge window
  auto cp2 = [&]() {
    if (g < NPAIRS) {
      copy_pair(g);
      copy_pair(g + 1);
      g += 2;
    }
  };

  // dep blocks copy own range while polling (RELAXED spin); then ONE acquire per dep
  if (depA >= 0 || depB >= 0) {
    for (;;) {
      __syncthreads();
      if (tid == 0) {
        int ok = 1;
        if (depA >= 0 &&
            __hip_atomic_load(&done[depA], __ATOMIC_RELAXED, __HIP_MEMORY_SCOPE_AGENT) == 0)
          ok = 0;
        if (ok && depB >= 0 &&
            __hip_atomic_load(&done[depB], __ATOMIC_RELAXED, __HIP_MEMORY_SCOPE_AGENT) == 0)
          ok = 0;
        sMeta[4] = ok;
      }
      __syncthreads();
      if (sMeta[4]) break;
      if (g < NPAIRS) {
        copy_pair(g);
        copy_pair(g + 1);
        g += 2;
      } else {
        __builtin_amdgcn_s_sleep(16);
      }
    }
    if (tid == 0) {
      if (depA >= 0)
        (void)__hip_atomic_load(&done[depA], __ATOMIC_ACQUIRE, __HIP_MEMORY_SCOPE_AGENT);
      if (depB >= 0)
        (void)__hip_atomic_load(&done[depB], __ATOMIC_ACQUIRE, __HIP_MEMORY_SCOPE_AGENT);
    }
    __syncthreads();
  }

  // stage embeddings (first touch from inputs, else chain state in out)
  const float* exg = (depA >= 0) ? out + (size_t)a * 4096 : inputs + (size_t)a * 4096;
  const float* eyg = (depB >= 0) ? out + (size_t)b * 4096 : inputs + (size_t)b * 4096;
#pragma unroll
  for (int k = 0; k < 2; ++k) {
    int i4 = tid + k * NT;
    int r = i4 >> 4, c4 = (i4 & 15) << 2;
    *(float4*)&sEx[r][c4] = *(const float4*)(exg + r * S + c4);
    *(float4*)&sEy[r][c4] = *(const float4*)(eyg + r * S + c4);
  }
  __syncthreads();

  // --- thread tiling: rows {ty, ty+32}, cols c0..c0+3 ---
  const int ty = tid >> 4;  // 0..31
  const int tx = tid & 15;  // 0..15
  const int c0 = tx << 2;

  // D[i][h] = sum_j A[i][j] * WT[j][h]
  auto proj = [&](const float (*A)[ST], const float (*WT)[ST], float (*D)[ST]) {
    float acc[2][4] = {};
#pragma unroll 4
    for (int j0 = 0; j0 < S; j0 += 4) {
      float4 av[2];
      av[0] = *(const float4*)&A[ty][j0];
      av[1] = *(const float4*)&A[ty + 32][j0];
#pragma unroll
      for (int jj = 0; jj < 4; ++jj) {
        float4 w4 = *(const float4*)&WT[j0 + jj][c0];
#pragma unroll
        for (int s = 0; s < 2; ++s) {
          float as = (&av[s].x)[jj];
          acc[s][0] = fmaf(as, w4.x, acc[s][0]);
          acc[s][1] = fmaf(as, w4.y, acc[s][1]);
          acc[s][2] = fmaf(as, w4.z, acc[s][2]);
          acc[s][3] = fmaf(as, w4.w, acc[s][3]);
        }
      }
    }
    *(float4*)&D[ty][c0] = make_float4(acc[0][0], acc[0][1], acc[0][2], acc[0][3]);
    *(float4*)&D[ty + 32][c0] = make_float4(acc[1][0], acc[1][1], acc[1][2], acc[1][3]);
  };

  // scores -> sP; cols cu = tx + 16u; wave-uniform chunk skip; masked cols get 0.0f
  auto score_phase = [&](int vlen) {
    if (vlen == 0) {  // softmax of all -1e6 = uniform 1/64
#pragma unroll
      for (int u = 0; u < 4; ++u) {
        sP[ty][tx + 16 * u] = 0.015625f;
        sP[ty + 32][tx + 16 * u] = 0.015625f;
      }
      return;
    }
    float acc[2][4] = {};
#pragma unroll 2
    for (int h0 = 0; h0 < S; h0 += 4) {
      float4 q4[2];
      q4[0] = *(const float4*)&sQ[ty][h0];
      q4[1] = *(const float4*)&sQ[ty + 32][h0];
      float4 wv4 = *(const float4*)&swv[h0];
#pragma unroll
      for (int u = 0; u < 4; ++u) {
        if (16 * u < vlen) {  // wave-uniform chunk skip
          float4 k4 = *(const float4*)&sK[tx + 16 * u][h0];
#pragma unroll
          for (int jj = 0; jj < 4; ++jj) {
            float kk = (&k4.x)[jj];
            float wvh = (&wv4.x)[jj];
            acc[0][u] = fmaf(tanh_term((&q4[0].x)[jj] + kk), wvh, acc[0][u]);
            acc[1][u] = fmaf(tanh_term((&q4[1].x)[jj] + kk), wvh, acc[1][u]);
          }
        }
      }
    }
#pragma unroll
    for (int u = 0; u < 4; ++u) {
      int cu = tx + 16 * u;
      sP[ty][cu] = (cu < vlen) ? acc[0][u] : 0.0f;      // zeros feed pv tail
      sP[ty + 32][cu] = (cu < vlen) ? acc[1][u] : 0.0f;
    }
  };

  // row softmax over cols < vlen: 8 lanes per row
  auto softmax_phase = [&](int vlen) {
    if (vlen == 0) return;  // already uniform
    const int row = tid >> 3, sub = tid & 7;
    float m = -3.0e38f;
#pragma unroll
    for (int k = 0; k < 8; ++k) {
      int c = sub + 8 * k;
      if (c < vlen) m = fmaxf(m, sP[row][c]);
    }
#pragma unroll
    for (int d = 1; d < 8; d <<= 1) m = fmaxf(m, __shfl_xor(m, d, 8));
    float p[8];
    float sum = 0.f;
#pragma unroll
    for (int k = 0; k < 8; ++k) {
      int c = sub + 8 * k;
      if (c < vlen) {
        p[k] = __expf(sP[row][c] - m);
        sum += p[k];
      }
    }
#pragma unroll
    for (int d = 1; d < 8; d <<= 1) sum += __shfl_xor(sum, d, 8);
    float inv = 1.0f / sum;
#pragma unroll
    for (int k = 0; k < 8; ++k) {
      int c = sub + 8 * k;
      if (c < vlen) sP[row][c] = p[k] * inv;
    }
  };

  // D[i][j] = sum_k P[i][k] * V[k][j]; k truncated to rounded vlen (zeros beyond)
  auto pv_phase = [&](const float (*V)[ST], float (*D)[ST], int vlen) {
    const int kEnd = (vlen == 0) ? S : ((vlen + 3) & ~3);
    float acc[2][4] = {};
    for (int k0 = 0; k0 < kEnd; k0 += 4) {
      float4 p4[2];
      p4[0] = *(const float4*)&sP[ty][k0];
      p4[1] = *(const float4*)&sP[ty + 32][k0];
#pragma unroll
      for (int kk = 0; kk < 4; ++kk) {
        float4 v4 = *(const float4*)&V[k0 + kk][c0];
#pragma unroll
        for (int s = 0; s < 2; ++s) {
          float ps = (&p4[s].x)[kk];
          acc[s][0] = fmaf(ps, v4.x, acc[s][0]);
          acc[s][1] = fmaf(ps, v4.y, acc[s][1]);
          acc[s][2] = fmaf(ps, v4.z, acc[s][2]);
          acc[s][3] = fmaf(ps, v4.w, acc[s][3]);
        }
      }
    }
    *(float4*)&D[ty][c0] = make_float4(acc[0][0], acc[0][1], acc[0][2], acc[0][3]);
    *(float4*)&D[ty + 32][c0] = make_float4(acc[1][0], acc[1][1], acc[1][2], acc[1][3]);
  };

  // out[h][c] = bfc[h] + sum_r Wfc[h][r]*E1[r][c] + sum_r Wfc[h][64+r]*A1[r][c]
  auto fc_phase = [&](const float (*E1)[ST], const float (*A1)[ST], float* outg) {
    float acc[2][4];
#pragma unroll
    for (int s = 0; s < 2; ++s) {
      float bv = sbfc[ty + 32 * s];
      acc[s][0] = bv; acc[s][1] = bv; acc[s][2] = bv; acc[s][3] = bv;
    }
#pragma unroll 2
    for (int r0 = 0; r0 < S; r0 += 4) {
      float4 w4[2];
      w4[0] = *(const float4*)&sWfc[ty][r0];
      w4[1] = *(const float4*)&sWfc[ty + 32][r0];
#pragma unroll
      for (int rr = 0; rr < 4; ++rr) {
        float4 e4 = *(const float4*)&E1[r0 + rr][c0];
#pragma unroll
        for (int s = 0; s < 2; ++s) {
          float ws = (&w4[s].x)[rr];
          acc[s][0] = fmaf(ws, e4.x, acc[s][0]);
          acc[s][1] = fmaf(ws, e4.y, acc[s][1]);
          acc[s][2] = fmaf(ws, e4.z, acc[s][2]);
          acc[s][3] = fmaf(ws, e4.w, acc[s][3]);
        }
      }
    }
#pragma unroll 2
    for (int r0 = 0; r0 < S; r0 += 4) {
      float4 w4[2];
      w4[0] = *(const float4*)&sWfc[ty][S + r0];
      w4[1] = *(const float4*)&sWfc[ty + 32][S + r0];
#pragma unroll
      for (int rr = 0; rr < 4; ++rr) {
        float4 e4 = *(const float4*)&A1[r0 + rr][c0];
#pragma unroll
        for (int s = 0; s < 2; ++s) {
          float ws = (&w4[s].x)[rr];
          acc[s][0] = fmaf(ws, e4.x, acc[s][0]);
          acc[s][1] = fmaf(ws, e4.y, acc[s][1]);
          acc[s][2] = fmaf(ws, e4.z, acc[s][2]);
          acc[s][3] = fmaf(ws, e4.w, acc[s][3]);
        }
      }
    }
    *(float4*)(outg + (size_t)ty * S + c0) =
        make_float4(acc[0][0], acc[0][1], acc[0][2], acc[0][3]);
    *(float4*)(outg + (size_t)(ty + 32) * S + c0) =
        make_float4(acc[1][0], acc[1][1], acc[1][2], acc[1][3]);
  };

  // ---- attention 1: q from ex, kv = ey, vlen = valid[a] ----
  // copy slots (cp2) at every phase boundary fill the HBM-idle edge window
  proj(sEx, sWqT, sQ);
  proj(sEy, sWkT, sK);
  cp2();
  __syncthreads();
  score_phase(validA);
  cp2();
  __syncthreads();
  softmax_phase(validA);
  cp2();
  cp2();
  __syncthreads();
  pv_phase(sEy, sQ, validA);  // sQ := y2x
  cp2();
  __syncthreads();
  fc_phase(sEx, sQ, out + (size_t)a * 4096);
  cp2();
  __syncthreads();

  // ---- attention 2: q from ey, kv = ex, vlen = valid[b] ----
  proj(sEy, sWqT, sQ);
  proj(sEx, sWkT, sK);
  cp2();
  __syncthreads();
  score_phase(validB);
  cp2();
  __syncthreads();
  softmax_phase(validB);
  cp2();
  cp2();
  __syncthreads();
  pv_phase(sEx, sQ, validB);  // sQ := x2y
  cp2();
  __syncthreads();
  fc_phase(sEy, sQ, out + (size_t)b * 4096);  // y written last -> wins on self-loop

  // __syncthreads drains every wave's stores; RELEASE store orders them at agent scope
  __syncthreads();
  if (tid == 0)
    __hip_atomic_store(&done[e], 1, __ATOMIC_RELEASE, __HIP_MEMORY_SCOPE_AGENT);

  // ---- finish this block's static copy range (barrier-free streaming) ----
  for (; g < NPAIRS; g += 2) {
    copy_pair(g);
    copy_pair(g + 1);
  }
}

extern "C" void kernel_launch(void* const* d_in, const int* in_sizes, int n_in,
                              void* d_out, int out_size, void* d_ws, size_t ws_size,
                              hipStream_t stream) {
  const float* inputs = (const float*)d_in[0];
  const int* masks = (const int*)d_in[1];
  const int* edges = (const int*)d_in[2];
  const float* Wq = (const float*)d_in[3];
  const float* Wk = (const float*)d_in[4];
  const float* wv = (const float*)d_in[5];
  const float* Wfc = (const float*)d_in[6];
  const float* bfc = (const float*)d_in[7];
  float* out = (float*)d_out;
  int* done = (int*)d_ws;                                  // 256 ints
  unsigned int* bitmap = (unsigned int*)(done + E_EDGES);  // 1024 words

  init_kernel<<<1, 1024, 0, stream>>>(edges, done, bitmap);
  fused_kernel<<<E_EDGES, NT, 0, stream>>>(inputs, masks, edges, Wq, Wk, wv, Wfc,
                                           bfc, out, done, bitmap);
}